// Round 4
// baseline (115.250 us; speedup 1.0000x reference)
//
#include <hip/hip_runtime.h>
#include <math.h>

// DotProductAttention: B=1,H=16,S=4096,D=64, fp32 in/out, no scale.
// Two-phase: (1) prepack K/V -> fp16 fragment-order tiles in d_ws,
// (2) 8-wave flash-attn, mfma_f32_32x32x16_f16, swapped QK^T, in-register
// softmax, global_load_lds staging, 3-buffer pipeline, 1 barrier/tile,
// counted vmcnt (never drained in main loop).

#define HH 16
#define SS 4096
#define DDm 64
#define WAVES 8
#define QBW 32
#define QB (WAVES * QBW)
#define KB 64
#define NTL (SS / KB)
#define LDP 72  // fallback kernel stride

typedef __attribute__((ext_vector_type(2))) _Float16 half2_t;
typedef __attribute__((ext_vector_type(4))) _Float16 half4_t;
typedef __attribute__((ext_vector_type(8))) _Float16 half8_t;
typedef __attribute__((ext_vector_type(16))) float f32x16;

union H8 { half2_t h2[4]; half8_t v; };
union FU { float f; unsigned u; };
union HU { half2_t h; unsigned u; };

__device__ inline unsigned asu(float x){ FU c; c.f=x; return c.u; }
__device__ inline float    asf(unsigned x){ FU c; c.u=x; return c.f; }
__device__ inline unsigned h2u(half2_t x){ HU c; c.h=x; return c.u; }
__device__ inline half2_t  u2h(unsigned x){ HU c; c.u=x; return c.h; }
__device__ inline half2_t  pk2(float a, float b){ half2_t h; h[0]=(_Float16)a; h[1]=(_Float16)b; return h; }

#if __has_builtin(__builtin_amdgcn_permlane32_swap)
#define HAVE_PL32 1
typedef __attribute__((ext_vector_type(2))) unsigned uint2_t;
__device__ inline uint2_t pl32(unsigned a, unsigned b){
  return __builtin_amdgcn_permlane32_swap(a, b, false, false);
}
#endif

#if __has_builtin(__builtin_amdgcn_exp2f)
#define EXP2F(x) __builtin_amdgcn_exp2f(x)
#else
#define EXP2F(x) exp2f(x)
#endif
#define L2E 1.44269504088896f

#define WAITVM(n) asm volatile("s_waitcnt vmcnt(" #n ")" ::: "memory")

__device__ __forceinline__ void gload16(const void* g, void* l) {
  __builtin_amdgcn_global_load_lds(
      (const __attribute__((address_space(1))) unsigned int*)g,
      (__attribute__((address_space(3))) unsigned int*)l, 16, 0, 0);
}

// ---------------- pre-pack: K/V fp32 -> fp16 fragment-order tiles ----------------
// K tile (h,t): elem (r, d=8*dg+e) at half-index (dg*64 + r)*8 + e   (8 KB/tile)
// V tile (h,t): elem (kv=8*kg+e, d_row) at (kg*64 + d_row)*8 + e     (transposed)
__global__ __launch_bounds__(256)
void prepack(const float* __restrict__ K, const float* __restrict__ V,
             _Float16* __restrict__ Kh, _Float16* __restrict__ Vth) {
  const int g = blockIdx.x;
  const int tid = threadIdx.x;
  if (g < 2048) {
    const int gt = g * 256 + tid;
    const int dg = gt & 7, r = (gt >> 3) & 63, t = (gt >> 9) & 63, h = gt >> 15;
    const float* src = K + ((size_t)(h * SS + t * 64 + r)) * DDm + dg * 8;
    float4 a = *(const float4*)src;
    float4 b = *(const float4*)(src + 4);
    H8 w;
    w.h2[0] = pk2(a.x, a.y); w.h2[1] = pk2(a.z, a.w);
    w.h2[2] = pk2(b.x, b.y); w.h2[3] = pk2(b.z, b.w);
    *(half8_t*)(Kh + (size_t)(h * 64 + t) * 4096 + (dg * 64 + r) * 8) = w.v;
  } else {
    const int gt = (g - 2048) * 256 + tid;
    const int dr = gt & 63, kg = (gt >> 6) & 7, t = (gt >> 9) & 63, h = gt >> 15;
    const float* src = V + ((size_t)(h * SS + t * 64 + kg * 8)) * DDm + dr;
    H8 w;
#pragma unroll
    for (int j = 0; j < 4; ++j)
      w.h2[j] = pk2(src[(2 * j) * DDm], src[(2 * j + 1) * DDm]);
    *(half8_t*)(Vth + (size_t)(h * 64 + t) * 4096 + (kg * 64 + dr) * 8) = w.v;
  }
}

// ---------------- main attention kernel ----------------
__global__ __launch_bounds__(512, 2)
void attn_main(const float* __restrict__ Q, const _Float16* __restrict__ Kh,
               const _Float16* __restrict__ Vth, float* __restrict__ O) {
  __shared__ __align__(16) _Float16 Kbuf[3][4096];
  __shared__ __align__(16) _Float16 Vbuf[3][4096];

  const int tid  = threadIdx.x;
  const int lane = tid & 63;
  const int lo5  = lane & 31;
  const int hi   = lane >> 5;
  const int wv   = tid >> 6;

  const int lid  = blockIdx.x;
  const int head = 2 * (lid & 7) + ((lid >> 3) & 1);  // head-pair per XCD
  const int qt   = lid >> 4;
  const int qbase = qt * QB + wv * QBW;
  const size_t hoff = (size_t)head * SS * DDm;

  // Q B-frags: lane holds Q[qbase+lo5][16ds+8hi+e]
  H8 qf[4];
  {
    const float* qp = Q + hoff + (size_t)(qbase + lo5) * DDm;
#pragma unroll
    for (int ds = 0; ds < 4; ++ds) {
      float4 a = *(const float4*)(qp + 16 * ds + 8 * hi);
      float4 b = *(const float4*)(qp + 16 * ds + 8 * hi + 4);
      qf[ds].h2[0] = pk2(a.x, a.y); qf[ds].h2[1] = pk2(a.z, a.w);
      qf[ds].h2[2] = pk2(b.x, b.y); qf[ds].h2[3] = pk2(b.z, b.w);
    }
  }

  const _Float16* kt0 = Kh + (size_t)head * 64 * 4096;
  const _Float16* vt0 = Vth + (size_t)head * 64 * 4096;

  f32x16 acc[2];
#pragma unroll
  for (int nt = 0; nt < 2; ++nt)
#pragma unroll
    for (int r = 0; r < 16; ++r) acc[nt][r] = 0.f;
  float m_run = -INFINITY, l_run = 0.f;

  // prologue: tiles 0,1 in flight
  gload16(kt0 + (size_t)tid * 8, &Kbuf[0][wv * 512]);
  gload16(vt0 + (size_t)tid * 8, &Vbuf[0][wv * 512]);
  gload16(kt0 + 4096 + (size_t)tid * 8, &Kbuf[1][wv * 512]);
  gload16(vt0 + 4096 + (size_t)tid * 8, &Vbuf[1][wv * 512]);

  int bc = 0;
  for (int t = 0; t < NTL; ++t) {
    if (t < NTL - 1) { WAITVM(2); } else { WAITVM(0); }
    __builtin_amdgcn_s_barrier();
    __builtin_amdgcn_sched_barrier(0);
    if (t + 2 < NTL) {
      int bi = bc + 2; if (bi >= 3) bi -= 3;
      gload16(kt0 + (size_t)(t + 2) * 4096 + (size_t)tid * 8, &Kbuf[bi][wv * 512]);
      gload16(vt0 + (size_t)(t + 2) * 4096 + (size_t)tid * 8, &Vbuf[bi][wv * 512]);
    }

    // all fragment reads for this tile (contiguous 16B wave accesses, conflict-free)
    half8_t kf[2][4];
#pragma unroll
    for (int s = 0; s < 2; ++s)
#pragma unroll
      for (int ds = 0; ds < 4; ++ds)
        kf[s][ds] = *(const half8_t*)&Kbuf[bc][((ds * 2 + hi) * 64 + 32 * s + lo5) * 8];
    half8_t vfr[2][2][2];
#pragma unroll
    for (int s = 0; s < 2; ++s)
#pragma unroll
      for (int sp = 0; sp < 2; ++sp)
#pragma unroll
        for (int nt = 0; nt < 2; ++nt)
          vfr[s][sp][nt] = *(const half8_t*)&Vbuf[bc][(((s * 2 + sp) * 2 + hi) * 64 + nt * 32 + lo5) * 8];

#pragma unroll
    for (int s = 0; s < 2; ++s) {
      f32x16 st;
#pragma unroll
      for (int r = 0; r < 16; ++r) st[r] = 0.f;
#pragma unroll
      for (int ds = 0; ds < 4; ++ds)
        st = __builtin_amdgcn_mfma_f32_32x32x16_f16(kf[s][ds], qf[ds].v, st, 0, 0, 0);

      // tree row-max
      float a0 = fmaxf(st[0], st[1]),   a1 = fmaxf(st[2], st[3]);
      float a2 = fmaxf(st[4], st[5]),   a3 = fmaxf(st[6], st[7]);
      float a4 = fmaxf(st[8], st[9]),   a5 = fmaxf(st[10], st[11]);
      float a6 = fmaxf(st[12], st[13]), a7 = fmaxf(st[14], st[15]);
      float b0 = fmaxf(a0, a1), b1 = fmaxf(a2, a3);
      float b2 = fmaxf(a4, a5), b3 = fmaxf(a6, a7);
      float tmax = fmaxf(fmaxf(b0, b1), fmaxf(b2, b3));
#if HAVE_PL32
      { uint2_t pr = pl32(asu(tmax), asu(tmax)); tmax = fmaxf(asf(pr[0]), asf(pr[1])); }
#else
      tmax = fmaxf(tmax, __shfl_xor(tmax, 32, 64));
#endif
      // defer-max rescale (rare)
      if (__any(tmax > m_run + 8.f)) {
        float mnew = fmaxf(m_run, tmax);
        float corr = EXP2F((m_run - mnew) * L2E);
        m_run = mnew; l_run *= corr;
#pragma unroll
        for (int r = 0; r < 16; ++r) {
          const int qr = (r & 3) + 8 * (r >> 2) + 4 * hi;
          float cf = asf(__builtin_amdgcn_ds_bpermute(qr << 2, asu(corr)));
          acc[0][r] *= cf; acc[1][r] *= cf;
        }
      }

      // exp + 4-chain sum
      const float mt = m_run * L2E;
      float p[16];
      float s0 = 0.f, s1 = 0.f, s2 = 0.f, s3 = 0.f;
#pragma unroll
      for (int r = 0; r < 16; r += 4) {
        p[r]     = EXP2F(__builtin_fmaf(st[r],     L2E, -mt)); s0 += p[r];
        p[r + 1] = EXP2F(__builtin_fmaf(st[r + 1], L2E, -mt)); s1 += p[r + 1];
        p[r + 2] = EXP2F(__builtin_fmaf(st[r + 2], L2E, -mt)); s2 += p[r + 2];
        p[r + 3] = EXP2F(__builtin_fmaf(st[r + 3], L2E, -mt)); s3 += p[r + 3];
      }
      float lsum = (s0 + s1) + (s2 + s3);
#if HAVE_PL32
      { uint2_t pr = pl32(asu(lsum), asu(lsum)); lsum = asf(pr[0]) + asf(pr[1]); }
#else
      lsum += __shfl_xor(lsum, 32, 64);
#endif
      l_run += lsum;

      // pack P -> PV A-frags
      H8 pa[2];
#pragma unroll
      for (int step = 0; step < 2; ++step) {
        const int b = 8 * step;
        half2_t x0 = pk2(p[b + 0], p[b + 1]);
        half2_t x1 = pk2(p[b + 2], p[b + 3]);
        half2_t y0 = pk2(p[b + 4], p[b + 5]);
        half2_t y1 = pk2(p[b + 6], p[b + 7]);
#if HAVE_PL32
        uint2_t sA = pl32(h2u(x0), h2u(y0));
        uint2_t sB = pl32(h2u(x1), h2u(y1));
        pa[step].h2[0] = u2h(sA[0]); pa[step].h2[1] = u2h(sB[0]);
        pa[step].h2[2] = u2h(sA[1]); pa[step].h2[3] = u2h(sB[1]);
#else
        half2_t sx0 = u2h(__shfl_xor(h2u(x0), 32, 64));
        half2_t sx1 = u2h(__shfl_xor(h2u(x1), 32, 64));
        half2_t sy0 = u2h(__shfl_xor(h2u(y0), 32, 64));
        half2_t sy1 = u2h(__shfl_xor(h2u(y1), 32, 64));
        pa[step].h2[0] = hi ? sy0 : x0;  pa[step].h2[1] = hi ? sy1 : x1;
        pa[step].h2[2] = hi ? y0 : sx0;  pa[step].h2[3] = hi ? y1 : sx1;
#endif
      }
#pragma unroll
      for (int step = 0; step < 2; ++step)
#pragma unroll
        for (int nt = 0; nt < 2; ++nt)
          acc[nt] = __builtin_amdgcn_mfma_f32_32x32x16_f16(pa[step].v, vfr[s][step][nt], acc[nt], 0, 0, 0);
    }

    bc += 1; if (bc >= 3) bc = 0;
  }

  const float invl = 1.f / l_run;
#pragma unroll
  for (int r = 0; r < 16; ++r) {
    const int qr = (r & 3) + 8 * (r >> 2) + 4 * hi;
    float il = asf(__builtin_amdgcn_ds_bpermute(qr << 2, asu(invl)));
    float* op = O + hoff + (size_t)(qbase + qr) * DDm + lo5;
    op[0]  = acc[0][r] * il;
    op[32] = acc[1][r] * il;
  }
}

// ---------------- fallback (round-3 kernel, used if ws too small) ----------------
__global__ __launch_bounds__(512, 2)
void attn_fwd_fb(const float* __restrict__ Q, const float* __restrict__ K,
                 const float* __restrict__ V, float* __restrict__ O) {
  __shared__ __align__(16) _Float16 Klds[2][KB][LDP];
  __shared__ __align__(16) _Float16 Vt  [2][DDm][LDP];

  const int tid  = threadIdx.x;
  const int lane = tid & 63;
  const int lo5  = lane & 31;
  const int hi   = lane >> 5;

  const int lid  = blockIdx.x;
  const int head = 2 * (lid & 7) + ((lid >> 3) & 1);
  const int qt   = lid >> 4;
  const int qbase = qt * QB + (tid >> 6) * QBW;
  const size_t hoff = (size_t)head * SS * DDm;

  H8 qf[4];
  {
    const float* qp = Q + hoff + (size_t)(qbase + lo5) * DDm;
#pragma unroll
    for (int ds = 0; ds < 4; ++ds) {
      float4 a = *(const float4*)(qp + 16 * ds + 8 * hi);
      float4 b = *(const float4*)(qp + 16 * ds + 8 * hi + 4);
      qf[ds].h2[0] = pk2(a.x, a.y); qf[ds].h2[1] = pk2(a.z, a.w);
      qf[ds].h2[2] = pk2(b.x, b.y); qf[ds].h2[3] = pk2(b.z, b.w);
    }
  }

  const int krow = tid >> 3, kc8 = (tid & 7) * 8;
  const int vd = tid & 63, vk8 = (tid >> 6) * 8;

  float4 ka, kb; float va[8];
  auto issue = [&](int t) {
    const float* kp = K + hoff + (size_t)(t * KB + krow) * DDm + kc8;
    ka = *(const float4*)kp;
    kb = *(const float4*)(kp + 4);
    const float* vp = V + hoff + (size_t)(t * KB + vk8) * DDm + vd;
#pragma unroll
    for (int j = 0; j < 8; ++j) va[j] = vp[j * DDm];
  };
  auto wstage = [&](int buf) {
    H8 kw;
    kw.h2[0] = pk2(ka.x, ka.y); kw.h2[1] = pk2(ka.z, ka.w);
    kw.h2[2] = pk2(kb.x, kb.y); kw.h2[3] = pk2(kb.z, kb.w);
    *(half8_t*)&Klds[buf][krow][kc8] = kw.v;
    H8 vw;
#pragma unroll
    for (int j = 0; j < 4; ++j) vw.h2[j] = pk2(va[2 * j], va[2 * j + 1]);
    *(half8_t*)&Vt[buf][vd][vk8] = vw.v;
  };

  f32x16 acc[2];
#pragma unroll
  for (int nt = 0; nt < 2; ++nt)
#pragma unroll
    for (int r = 0; r < 16; ++r) acc[nt][r] = 0.f;
  float m_run = -INFINITY, l_run = 0.f;

  issue(0); wstage(0); __syncthreads();

  for (int t = 0; t < NTL; ++t) {
    const int cur = t & 1;
    if (t + 1 < NTL) issue(t + 1);

#pragma unroll
    for (int s = 0; s < 2; ++s) {
      const int rs = 32 * s;
      f32x16 st;
#pragma unroll
      for (int r = 0; r < 16; ++r) st[r] = 0.f;
#pragma unroll
      for (int ds = 0; ds < 4; ++ds) {
        half8_t af = *(const half8_t*)&Klds[cur][rs + lo5][16 * ds + 8 * hi];
        st = __builtin_amdgcn_mfma_f32_32x32x16_f16(af, qf[ds].v, st, 0, 0, 0);
      }
      float tmax = st[0];
#pragma unroll
      for (int r = 1; r < 16; ++r) tmax = fmaxf(tmax, st[r]);
#if HAVE_PL32
      { uint2_t pr = pl32(asu(tmax), asu(tmax)); tmax = fmaxf(asf(pr[0]), asf(pr[1])); }
#else
      tmax = fmaxf(tmax, __shfl_xor(tmax, 32, 64));
#endif
      if (__any(tmax > m_run + 8.f)) {
        float mnew = fmaxf(m_run, tmax);
        float corr = __expf(m_run - mnew);
        m_run = mnew; l_run *= corr;
#pragma unroll
        for (int r = 0; r < 16; ++r) {
          const int qr = (r & 3) + 8 * (r >> 2) + 4 * hi;
          float cf = asf(__builtin_amdgcn_ds_bpermute(qr << 2, asu(corr)));
          acc[0][r] *= cf; acc[1][r] *= cf;
        }
      }
      float p[16]; float lsum = 0.f;
#pragma unroll
      for (int r = 0; r < 16; ++r) { p[r] = __expf(st[r] - m_run); lsum += p[r]; }
#if HAVE_PL32
      { uint2_t pr = pl32(asu(lsum), asu(lsum)); lsum = asf(pr[0]) + asf(pr[1]); }
#else
      lsum += __shfl_xor(lsum, 32, 64);
#endif
      l_run += lsum;
      H8 pa[2];
#pragma unroll
      for (int step = 0; step < 2; ++step) {
        const int b = 8 * step;
        half2_t x0 = pk2(p[b + 0], p[b + 1]);
        half2_t x1 = pk2(p[b + 2], p[b + 3]);
        half2_t y0 = pk2(p[b + 4], p[b + 5]);
        half2_t y1 = pk2(p[b + 6], p[b + 7]);
#if HAVE_PL32
        uint2_t sA = pl32(h2u(x0), h2u(y0));
        uint2_t sB = pl32(h2u(x1), h2u(y1));
        pa[step].h2[0] = u2h(sA[0]); pa[step].h2[1] = u2h(sB[0]);
        pa[step].h2[2] = u2h(sA[1]); pa[step].h2[3] = u2h(sB[1]);
#else
        half2_t sx0 = u2h(__shfl_xor(h2u(x0), 32, 64));
        half2_t sx1 = u2h(__shfl_xor(h2u(x1), 32, 64));
        half2_t sy0 = u2h(__shfl_xor(h2u(y0), 32, 64));
        half2_t sy1 = u2h(__shfl_xor(h2u(y1), 32, 64));
        pa[step].h2[0] = hi ? sy0 : x0;  pa[step].h2[1] = hi ? sy1 : x1;
        pa[step].h2[2] = hi ? y0 : sx0;  pa[step].h2[3] = hi ? y1 : sx1;
#endif
      }
#pragma unroll
      for (int step = 0; step < 2; ++step)
#pragma unroll
        for (int nt = 0; nt < 2; ++nt) {
          half8_t vb = *(const half8_t*)&Vt[cur][32 * nt + lo5][rs + 16 * step + 8 * hi];
          acc[nt] = __builtin_amdgcn_mfma_f32_32x32x16_f16(pa[step].v, vb, acc[nt], 0, 0, 0);
        }
    }

    __syncthreads();
    if (t + 1 < NTL) wstage((t + 1) & 1);
    __syncthreads();
  }

  const float invl = 1.f / l_run;
#pragma unroll
  for (int r = 0; r < 16; ++r) {
    const int qr = (r & 3) + 8 * (r >> 2) + 4 * hi;
    float il = asf(__builtin_amdgcn_ds_bpermute(qr << 2, asu(invl)));
    float* op = O + hoff + (size_t)(qbase + qr) * DDm + lo5;
    op[0]  = acc[0][r] * il;
    op[32] = acc[1][r] * il;
  }
}

extern "C" void kernel_launch(void* const* d_in, const int* in_sizes, int n_in,
                              void* d_out, int out_size, void* d_ws, size_t ws_size,
                              hipStream_t stream) {
  const float* Q = (const float*)d_in[0];
  const float* K = (const float*)d_in[1];
  const float* V = (const float*)d_in[2];
  float* O = (float*)d_out;
  const size_t need = (size_t)2 * HH * SS * DDm * sizeof(_Float16);  // 16 MiB
  if (ws_size >= need) {
    _Float16* Kh  = (_Float16*)d_ws;
    _Float16* Vth = Kh + (size_t)HH * SS * DDm;
    prepack<<<dim3(4096), dim3(256), 0, stream>>>(K, V, Kh, Vth);
    attn_main<<<dim3(256), dim3(512), 0, stream>>>(Q, Kh, Vth, O);
  } else {
    attn_fwd_fb<<<dim3(256), dim3(512), 0, stream>>>(Q, K, V, O);
  }
}